// Round 7
// baseline (726.616 us; speedup 1.0000x reference)
//
#include <hip/hip_runtime.h>
#include <math.h>

typedef unsigned short u16;
typedef unsigned int   u32;
typedef __attribute__((ext_vector_type(8))) short short8;
typedef __attribute__((ext_vector_type(4))) float floatx4;

#define MFMA16(a, b, c) __builtin_amdgcn_mfma_f32_16x16x32_bf16(a, b, c, 0, 0, 0)
#define LOG2E 1.4426950408889634f
#define EXP2(x) __builtin_amdgcn_exp2f(x)

__device__ __forceinline__ float b2f(u16 b) { return __uint_as_float(((u32)b) << 16); }
__device__ __forceinline__ u16 f2b(float f) {
  u32 x = __float_as_uint(f);
  return (u16)((x + 0x7FFFu + ((x >> 16) & 1u)) >> 16);
}
__device__ __forceinline__ short8 pack8(float4 a, float4 b) {
  short8 r;
  r[0] = (short)f2b(a.x); r[1] = (short)f2b(a.y); r[2] = (short)f2b(a.z); r[3] = (short)f2b(a.w);
  r[4] = (short)f2b(b.x); r[5] = (short)f2b(b.y); r[6] = (short)f2b(b.z); r[7] = (short)f2b(b.w);
  return r;
}
// async 16B global->LDS (wave-uniform LDS base + lane*16)
__device__ __forceinline__ void gload16(const u16* g, u16* l) {
  __builtin_amdgcn_global_load_lds(
      (const __attribute__((address_space(1))) u32*)g,
      (__attribute__((address_space(3))) u32*)l, 16, 0, 0);
}

// ---------------- prep: column bias (log2-domain) and value gate ----------------
__global__ void prep_kernel(const float* __restrict__ ppr, const float* __restrict__ trust,
                            const float* __restrict__ plpa, const float* __restrict__ ptsc,
                            const int* __restrict__ pnc,
                            float* __restrict__ colbias, float* __restrict__ vgate)
{
  const int i = blockIdx.x * 256 + threadIdx.x;   // grid 8 -> 2048
  const int n_ctx = pnc[0];
  const float lpa = plpa[0], ts = ptsc[0];
  if (i < 2048) {
    float cb = 0.0f, g = 1.0f;
    if (i < n_ctx) {
      cb = -lpa * logf(fmaxf(ppr[i], 1e-8f)) * LOG2E;
      g = 1.0f / (1.0f + expf(-ts * trust[i]));
    }
    colbias[i] = cb;
    vgate[i] = g;
  }
}

// ---------------- fp32 -> bf16 conversion passes ----------------
__global__ __launch_bounds__(256) void convert1(const float* __restrict__ X, const float* __restrict__ Wi,
                                                u16* __restrict__ Xb, u16* __restrict__ Wib)
{
  const size_t i = ((size_t)blockIdx.x * 256 + threadIdx.x) * 8;  // grid 5632 covers 11,534,336
  const float* src;
  u16* dst;
  if (i < 8388608) { src = X + i; dst = Xb + i; }
  else { src = Wi + (i - 8388608); dst = Wib + (i - 8388608); }
  float4 a = *(const float4*)src, b = *(const float4*)(src + 4);
  *(short8*)dst = pack8(a, b);
}

__global__ __launch_bounds__(256) void convert2(const float* __restrict__ Wo, u16* __restrict__ Wob)
{
  const size_t i = ((size_t)blockIdx.x * 256 + threadIdx.x) * 8;  // grid 512 -> 1,048,576
  float4 a = *(const float4*)(Wo + i), b = *(const float4*)(Wo + i + 4);
  *(short8*)(Wob + i) = pack8(a, b);
}

// ---------------- QKV projection: bf16 MFMA GEMM, BK=64 DMA-staged ----------------
// q -> [bh][n][64]; k -> pre-scaled by 0.125*log2e; v -> gated, transposed [bh][d][2048]
__global__ __launch_bounds__(256) void qkv_mfma(
    const u16* __restrict__ Xb, const u16* __restrict__ Wib, const float* __restrict__ bin,
    const float* __restrict__ vgate,
    u16* __restrict__ qW, u16* __restrict__ kW, u16* __restrict__ vT)
{
  __shared__ __align__(16) u16 SMEM[16384];     // As[2x128x32] | Bs[2x128x32] = 32 KB
  u16* As = SMEM;
  u16* Bs = SMEM + 8192;
  const int tid = threadIdx.x;
  const int wave = tid >> 6, lane = tid & 63;
  const int k15 = lane & 15, quad = lane >> 4;
  const int wm = wave & 1, wn = wave >> 1;
  const int m0 = blockIdx.y << 7, n0 = blockIdx.x << 7;

  // DMA addressing: sub-tile kk (32 cols), issue j: rows wave*32 + j*16 + lane/4
  const int rg = (wave << 5) + (lane >> 2);
  const int cc = (lane & 3) << 3;
  const u16* gA = Xb + (size_t)(m0 + rg) * 1024 + cc;
  const u16* gB = Wib + (size_t)(n0 + rg) * 1024 + cc;
  u16* lA = As + (wave << 10);
  u16* lB = Bs + (wave << 10);

  floatx4 c[4][4];
#pragma unroll
  for (int i = 0; i < 4; ++i)
#pragma unroll
    for (int j = 0; j < 4; ++j) c[i][j] = (floatx4){0.f, 0.f, 0.f, 0.f};

  for (int k0 = 0; k0 < 1024; k0 += 64) {
    __syncthreads();                            // prior iteration frag reads done
    gload16(gA + k0, lA);
    gload16(gA + k0 + 16384, lA + 512);
    gload16(gA + k0 + 32, lA + 4096);
    gload16(gA + k0 + 32 + 16384, lA + 4096 + 512);
    gload16(gB + k0, lB);
    gload16(gB + k0 + 16384, lB + 512);
    gload16(gB + k0 + 32, lB + 4096);
    gload16(gB + k0 + 32 + 16384, lB + 4096 + 512);
    __syncthreads();                            // vmcnt drained -> LDS tiles ready
#pragma unroll
    for (int kk = 0; kk < 2; ++kk) {
      short8 af[4], bf[4];
#pragma unroll
      for (int rt = 0; rt < 4; ++rt)
        af[rt] = *(const short8*)(As + kk * 4096 + (64 * wm + 16 * rt + k15) * 32 + quad * 8);
#pragma unroll
      for (int ct = 0; ct < 4; ++ct)
        bf[ct] = *(const short8*)(Bs + kk * 4096 + (64 * wn + 16 * ct + k15) * 32 + quad * 8);
#pragma unroll
      for (int rt = 0; rt < 4; ++rt)
#pragma unroll
        for (int ct = 0; ct < 4; ++ct)
          c[rt][ct] = MFMA16(af[rt], bf[ct], c[rt][ct]);
    }
  }

  const int which = n0 >> 10;                   // 0=q 1=k 2=v (block never crosses)
  const int b = m0 >> 11, nb = m0 & 2047;
  if (which < 2) {
    // q/k: stage C tile in LDS, coalesced short8 stores
    u16* dst0 = which ? kW : qW;
    const float ksc = which ? 0.125f * LOG2E : 1.0f;
    u16* T = SMEM;                              // 2 x (128 m x 64 d) = 16384 elems
    __syncthreads();
#pragma unroll
    for (int ct = 0; ct < 4; ++ct) {
      const int el = 64 * wn + 16 * ct + k15;   // 0..127
      const float bb = bin[n0 + el];
#pragma unroll
      for (int rt = 0; rt < 4; ++rt)
#pragma unroll
        for (int r = 0; r < 4; ++r) {
          const int ml = 64 * wm + 16 * rt + 4 * quad + r;
          T[(el >> 6) * 8192 + ml * 64 + (el & 63)] = f2b((c[rt][ct][r] + bb) * ksc);
        }
    }
    __syncthreads();
#pragma unroll
    for (int hh = 0; hh < 2; ++hh) {
      const int h = ((n0 + 64 * hh) >> 6) & 15;
      u16* dbase = dst0 + ((size_t)(b * 16 + h) * 2048 + nb) * 64;
#pragma unroll
      for (int j = 0; j < 4; ++j) {
        const int u = tid + j * 256;            // 0..1023
        const int row = u >> 3, c8 = (u & 7) << 3;
        short8 v = *(const short8*)(T + hh * 8192 + row * 64 + c8);
        *(short8*)(dbase + (size_t)row * 64 + c8) = v;
      }
    }
  } else {
    // v: gate, transpose 128x64 half-tiles through LDS -> vT[bh][d][2048]
    u16* T = SMEM;                              // 64 x 136 u16
    for (int half = 0; half < 2; ++half) {
      __syncthreads();
      if (wn == half) {
#pragma unroll
        for (int ct = 0; ct < 4; ++ct) {
          const int el = 16 * ct + k15;
          const int e = n0 + 64 * half + el;
          const float bb = bin[e];
#pragma unroll
          for (int rt = 0; rt < 4; ++rt)
#pragma unroll
            for (int r = 0; r < 4; ++r) {
              const int ml = 64 * wm + 16 * rt + 4 * quad + r;
              T[el * 136 + ml] = f2b((c[rt][ct][r] + bb) * vgate[nb + ml]);
            }
        }
      }
      __syncthreads();
#pragma unroll
      for (int uu = 0; uu < 4; ++uu) {
        const int u = tid + uu * 256;
        const int el = u >> 4, moct = u & 15;
        const int e = n0 + 64 * half + el;
        const int h = (e >> 6) & 15, d = e & 63;
        short8 vv = *(const short8*)(T + el * 136 + moct * 8);
        *(short8*)(vT + (((size_t)(b * 16 + h)) * 64 + d) * 2048 + nb + moct * 8) = vv;
      }
    }
  }
}

// ---------------- Flash attention: barrier-free, K/V frags direct from global ----------------
__global__ __launch_bounds__(256) void attn_mfma(
    const u16* __restrict__ qW, const u16* __restrict__ kW, const u16* __restrict__ vT,
    const float* __restrict__ colbias, u16* __restrict__ aO)
{
  __shared__ __align__(16) u16 Ps[4 * 16 * 72]; // per-wave P [q][key] pad 72
  __shared__ float exS[128];                    // per-wave 32: al / l exchange

  const int tid = threadIdx.x;
  const int wave = tid >> 6, lane = tid & 63;
  const int k15 = lane & 15, quad = lane >> 4;
  // XCD-aware swizzle: bh pinned to blockIdx%8 class -> each XCD L2 caches 8 bh of K/V
  const int bidx = blockIdx.x;
  const int bh = ((bidx & 7) << 3) + ((bidx >> 3) & 7);
  const int qt = bidx >> 6;                     // 0..31
  const size_t base = (size_t)bh * 2048 * 64;
  const size_t baseV = (size_t)bh * 64 * 2048;
  const int q0 = qt << 6;

  // Q fragment, reused as the B operand of K.Q^T every k-block
  const u16* qp = qW + base + (size_t)(q0 + 16 * wave + k15) * 64 + quad * 8;
  short8 qa0 = *(const short8*)qp;
  short8 qa1 = *(const short8*)(qp + 32);

  floatx4 o[4];
#pragma unroll
  for (int t = 0; t < 4; ++t) o[t] = (floatx4){0.f, 0.f, 0.f, 0.f};
  float m_i = -3.0e38f, l_i = 0.f;              // this lane's q = k15 (log2 domain)

  const u16* kfp = kW + base + (size_t)k15 * 64 + quad * 8;   // + (kb+16t)*64
  const u16* vfp = vT + baseV + (size_t)k15 * 2048 + quad * 8; // + 16t*2048 + kb

  for (int kb = 0; kb < 2048; kb += 64) {
    // S^T = K.Q^T: K fragments straight from global (A-op), acc init = column bias
    floatx4 s[4];
#pragma unroll
    for (int t = 0; t < 4; ++t) {
      float4 cb = *(const float4*)(colbias + kb + 16 * t + 4 * quad);
      const u16* kp = kfp + (size_t)(kb + 16 * t) * 64;
      short8 ka0 = *(const short8*)kp;
      short8 ka1 = *(const short8*)(kp + 32);
      s[t] = (floatx4){cb.x, cb.y, cb.z, cb.w};
      s[t] = MFMA16(ka0, qa0, s[t]);
      s[t] = MFMA16(ka1, qa1, s[t]);
    }

    // per-lane softmax over 16 in-register keys, then cross-quad butterfly
    float mx = s[0][0];
#pragma unroll
    for (int t = 0; t < 4; ++t)
#pragma unroll
      for (int r = 0; r < 4; ++r) mx = fmaxf(mx, s[t][r]);
    mx = fmaxf(mx, __shfl_xor(mx, 16));
    mx = fmaxf(mx, __shfl_xor(mx, 32));
    const float mn = fmaxf(m_i, mx);
    const float al = EXP2(m_i - mn);
    m_i = mn;
    float p[4][4];
    float sum = 0.f;
#pragma unroll
    for (int t = 0; t < 4; ++t)
#pragma unroll
      for (int r = 0; r < 4; ++r) {
        p[t][r] = EXP2(s[t][r] - mn);
        sum += p[t][r];
      }
    sum += __shfl_xor(sum, 16);
    sum += __shfl_xor(sum, 32);
    l_i = l_i * al + sum;

    // P[q][key] -> wave-private LDS (layout transform C->A), v_perm trunc pack
#pragma unroll
    for (int t = 0; t < 4; ++t) {
      u32 lo = __builtin_amdgcn_perm(__float_as_uint(p[t][1]), __float_as_uint(p[t][0]), 0x07060302u);
      u32 hi = __builtin_amdgcn_perm(__float_as_uint(p[t][3]), __float_as_uint(p[t][2]), 0x07060302u);
      *(uint2*)(Ps + wave * 1152 + k15 * 72 + 16 * t + 4 * quad) = (uint2){lo, hi};
    }

    // rescale O: al for q-rows 4*quad+r via wave-local LDS exchange
    float* aw = exS + wave * 32;
    if (quad == 0) aw[k15] = al;
    float4 al4 = *(const float4*)(aw + 4 * quad);
#pragma unroll
    for (int t = 0; t < 4; ++t)
#pragma unroll
      for (int r = 0; r < 4; ++r) o[t][r] *= al4[r];

    // O += P V: P from LDS (A-op), V fragments straight from global (B-op)
    const u16* pp = Ps + wave * 1152 + k15 * 72 + quad * 8;
    short8 pa0 = *(const short8*)pp;
    short8 pa1 = *(const short8*)(pp + 32);
#pragma unroll
    for (int t = 0; t < 4; ++t) {
      const u16* vp = vfp + (size_t)(16 * t) * 2048 + kb;
      short8 vb0 = *(const short8*)vp;
      short8 vb1 = *(const short8*)(vp + 32);
      o[t] = MFMA16(pa0, vb0, o[t]);
      o[t] = MFMA16(pa1, vb1, o[t]);
    }
  }

  // epilogue: exchange l, normalize, store aO [b][n][h*64+d]
  float* lw = exS + wave * 32 + 16;
  if (quad == 0) lw[k15] = l_i;
  float4 l4 = *(const float4*)(lw + 4 * quad);
  const int b = bh >> 4, h = bh & 15;
#pragma unroll
  for (int r = 0; r < 4; ++r) {
    const int q = q0 + 16 * wave + 4 * quad + r;
    const float inv = 1.0f / l4[r];
    u16* dst = aO + (size_t)(b * 2048 + q) * 1024 + h * 64;
#pragma unroll
    for (int t = 0; t < 4; ++t)
      dst[16 * t + k15] = f2b(o[t][r] * inv);
  }
}

// ---------------- Output projection: bf16 MFMA GEMM (BK=64 DMA), fp32 out ----------------
__global__ __launch_bounds__(256) void oproj_mfma(
    const u16* __restrict__ A, const u16* __restrict__ Wob, const float* __restrict__ bout,
    float* __restrict__ out)
{
  __shared__ __align__(16) u16 SMEM[16384];
  u16* As = SMEM;
  u16* Bs = SMEM + 8192;
  const int tid = threadIdx.x;
  const int wave = tid >> 6, lane = tid & 63;
  const int k15 = lane & 15, quad = lane >> 4;
  const int wm = wave & 1, wn = wave >> 1;
  const int m0 = blockIdx.y << 7, n0 = blockIdx.x << 7;

  const int rg = (wave << 5) + (lane >> 2);
  const int cc = (lane & 3) << 3;
  const u16* gA = A + (size_t)(m0 + rg) * 1024 + cc;
  const u16* gB = Wob + (size_t)(n0 + rg) * 1024 + cc;
  u16* lA = As + (wave << 10);
  u16* lB = Bs + (wave << 10);

  floatx4 c[4][4];
#pragma unroll
  for (int i = 0; i < 4; ++i)
#pragma unroll
    for (int j = 0; j < 4; ++j) c[i][j] = (floatx4){0.f, 0.f, 0.f, 0.f};

  for (int k0 = 0; k0 < 1024; k0 += 64) {
    __syncthreads();
    gload16(gA + k0, lA);
    gload16(gA + k0 + 16384, lA + 512);
    gload16(gA + k0 + 32, lA + 4096);
    gload16(gA + k0 + 32 + 16384, lA + 4096 + 512);
    gload16(gB + k0, lB);
    gload16(gB + k0 + 16384, lB + 512);
    gload16(gB + k0 + 32, lB + 4096);
    gload16(gB + k0 + 32 + 16384, lB + 4096 + 512);
    __syncthreads();
#pragma unroll
    for (int kk = 0; kk < 2; ++kk) {
      short8 af[4], bf[4];
#pragma unroll
      for (int rt = 0; rt < 4; ++rt)
        af[rt] = *(const short8*)(As + kk * 4096 + (64 * wm + 16 * rt + k15) * 32 + quad * 8);
#pragma unroll
      for (int ct = 0; ct < 4; ++ct)
        bf[ct] = *(const short8*)(Bs + kk * 4096 + (64 * wn + 16 * ct + k15) * 32 + quad * 8);
#pragma unroll
      for (int rt = 0; rt < 4; ++rt)
#pragma unroll
        for (int ct = 0; ct < 4; ++ct)
          c[rt][ct] = MFMA16(af[rt], bf[ct], c[rt][ct]);
    }
  }

#pragma unroll
  for (int ct = 0; ct < 4; ++ct) {
    const int e = n0 + 64 * wn + 16 * ct + k15;
    const float bb = bout[e];
#pragma unroll
    for (int rt = 0; rt < 4; ++rt)
#pragma unroll
      for (int r = 0; r < 4; ++r) {
        const int m = m0 + 64 * wm + 16 * rt + 4 * quad + r;
        out[(size_t)m * 1024 + e] = c[rt][ct][r] + bb;
      }
  }
}

extern "C" void kernel_launch(void* const* d_in, const int* in_sizes, int n_in,
                              void* d_out, int out_size, void* d_ws, size_t ws_size,
                              hipStream_t stream)
{
  const float* X     = (const float*)d_in[0];
  const int*   pnc   = (const int*)d_in[1];
  const float* ppr   = (const float*)d_in[2];
  const float* trust = (const float*)d_in[3];
  const float* Win   = (const float*)d_in[4];
  const float* bin   = (const float*)d_in[5];
  const float* Wout  = (const float*)d_in[6];
  const float* bout  = (const float*)d_in[7];
  const float* plpa  = (const float*)d_in[8];
  const float* ptsc  = (const float*)d_in[9];
  float* out = (float*)d_out;

  const size_t SZ = (size_t)64 * 2048 * 64;     // 8,388,608 elems = 16 MB bf16
  u16* Xb = (u16*)d_ws;                         // phase 1-2; aliased by aO in phase 3+
  u16* qW = Xb + SZ;
  u16* kW = qW + SZ;                            // phase 3; aliased by Wob in phase 4+
  u16* vT = kW + SZ;                            // [bh][d][2048]   (total ws = 64 MB)
  u16* aO = Xb;
  u16* Wob = kW;
  // scratch parked in d_out (fully overwritten by oproj at the end):
  float* colbias = (float*)d_out;               // [2048] (log2-domain)
  float* vgate   = colbias + 2048;              // [2048]
  u16*   Wib     = (u16*)(vgate + 2048);        // 3072x1024 bf16 = 6 MB

  prep_kernel<<<dim3(8), 256, 0, stream>>>(ppr, trust, plpa, ptsc, pnc, colbias, vgate);
  convert1<<<dim3(5632), 256, 0, stream>>>(X, Win, Xb, Wib);
  qkv_mfma<<<dim3(24, 64), 256, 0, stream>>>(Xb, Wib, bin, vgate, qW, kW, vT);
  attn_mfma<<<dim3(2048), 256, 0, stream>>>(qW, kW, vT, colbias, aO);
  convert2<<<dim3(512), 256, 0, stream>>>(Wout, Wob);
  oproj_mfma<<<dim3(8, 64), 256, 0, stream>>>(aO, Wob, bout, out);
}